// Round 1
// baseline (31314.636 us; speedup 1.0000x reference)
//
#include <hip/hip_runtime.h>
#include <cmath>

#define B_ 256
#define TH_ 512
#define TA_ 576

typedef unsigned short u16;
typedef __bf16 bf16x8 __attribute__((ext_vector_type(8)));
typedef short short8 __attribute__((ext_vector_type(8)));
typedef float f32x4 __attribute__((ext_vector_type(4)));

__device__ __forceinline__ f32x4 mfma_bf16(short8 a, short8 b, f32x4 c) {
  return __builtin_amdgcn_mfma_f32_16x16x32_bf16(
      __builtin_bit_cast(bf16x8, a), __builtin_bit_cast(bf16x8, b), c, 0, 0, 0);
}
__device__ __forceinline__ u16 f2bf(float f) {
  unsigned int u = __builtin_bit_cast(unsigned int, f);
  u = (u + 0x7fffu + ((u >> 16) & 1u)) >> 16;
  return (u16)u;
}
__device__ __forceinline__ float sigm(float x) { return 1.f / (1.f + __expf(-x)); }
__device__ __forceinline__ float tanh_fast(float x) { return 1.f - 2.f / (__expf(2.f * x) + 1.f); }
__device__ __forceinline__ float softplus_f(float x) { return fmaxf(x, 0.f) + log1pf(__expf(-fabsf(x))); }

// ---------------- prep kernels ----------------

// dst[n*R + k] = src[k*C + n]  (src is [R][C] fp32, dst is [C][R] bf16)
__global__ void k_transpose_cvt(const float* __restrict__ src, u16* __restrict__ dst, int R, int C) {
  int i = blockIdx.x * 256 + threadIdx.x;
  if (i >= R * C) return;
  int n = i / R, k = i - n * R;
  dst[i] = f2bf(src[(size_t)k * C + n]);
}

// W_comb transposed: dst[n*32 + p] = sum_d We[p][d] * Wih[d][n]  (p<16; cols 16..31 zero)
__global__ void k_wcomb(const float* __restrict__ We, const float* __restrict__ Wih, int N,
                        u16* __restrict__ dst) {
  int i = blockIdx.x * 256 + threadIdx.x;
  if (i >= N * 32) return;
  int n = i >> 5, p = i & 31;
  float s = 0.f;
  if (p < 16) {
    for (int d = 0; d < 512; ++d) s += We[p * 512 + d] * Wih[(size_t)d * N + n];
  }
  dst[i] = f2bf(s);
}

// bias_x[n] = sum_d be[d]*Wih[d][n] + bih[n] (+ bhh[n] if given)
__global__ void k_biasx(const float* __restrict__ be, const float* __restrict__ Wih,
                        const float* __restrict__ bih, const float* __restrict__ bhh, int N,
                        float* __restrict__ dst) {
  int n = blockIdx.x * 256 + threadIdx.x;
  if (n >= N) return;
  float s = bih[n];
  for (int d = 0; d < 512; ++d) s += be[d] * Wih[(size_t)d * N + n];
  if (bhh) s += bhh[n];
  dst[n] = s;
}

// zero sync counters; init y_hist to b_head + b_e2 . W_head
__global__ void k_init(int* __restrict__ cnt, int ncnt, float* __restrict__ y, int ny,
                       const float* __restrict__ b_e2, const float* __restrict__ Wh,
                       const float* __restrict__ b_head) {
  int i = blockIdx.x * 256 + threadIdx.x;
  if (i < ncnt) cnt[i] = 0;
  if (i < ny) {
    float s = b_head[0];
    for (int n = 0; n < 512; ++n) s += b_e2[n] * Wh[n];
    y[i] = s;
  }
}

// ---------------- persistent recurrence kernel ----------------
// LSTM: 4 groups (64 batch) x 16 slices (16 h-cols, 64 gate-cols). K=256.
// GRU : 4 groups (64 batch) x 32 slices (16 h-cols, 48 gate-cols). K=512.
// Weight slice resident in LDS (bf16, [n][k], padded row stride); previous h read
// from global (bf16) as MFMA A-fragments; per-(group,step) arrival counters.

__device__ __forceinline__ void lstm_path(
    int wg, const float* __restrict__ patches, const u16* __restrict__ Wt,
    const u16* __restrict__ Wc, const float* __restrict__ bias, u16* __restrict__ hbi,
    int halfoff, int* cnt, int fwd, u16* lds) {
  const int tid = threadIdx.x;
  const int lane = tid & 63, wv = tid >> 6;
  const int g = wg >> 4, s = wg & 15;
  const int b0 = g << 6;  // batch base
  const int c0 = s << 4;  // h-col base within 256
  u16* W_lds = lds;              // [64][264]
  u16* p_lds = lds + 64 * 264;   // [64][40]  (cols 16..31 zero)
  u16* Wc_lds = p_lds + 64 * 40; // [64][40]

  for (int idx = tid; idx < 2048; idx += 256) {
    int n = idx >> 5, k8 = (idx & 31) << 3;
    int grow = ((n >> 4) << 8) + c0 + (n & 15);
    *(short8*)&W_lds[n * 264 + k8] = *(const short8*)&Wt[(size_t)grow * 256 + k8];
  }
  {
    int idx = tid;
    if (idx < 256) {
      int n = idx >> 2, k8 = (idx & 3) << 3;
      int grow = ((n >> 4) << 8) + c0 + (n & 15);
      *(short8*)&Wc_lds[n * 40 + k8] = *(const short8*)&Wc[(size_t)grow * 32 + k8];
    }
  }
  for (int idx = tid; idx < 2560; idx += 256) p_lds[idx] = 0;

  const int cl = lane & 15, kq = lane >> 4;
  const float bs_i = bias[c0 + cl];
  const float bs_f = bias[256 + c0 + cl];
  const float bs_g = bias[512 + c0 + cl];
  const float bs_o = bias[768 + c0 + cl];
  const int m0 = wv << 4;
  f32x4 c_st = {0.f, 0.f, 0.f, 0.f};

  __syncthreads();

  for (int j = 0; j < TA_; ++j) {
    const int t = fwd ? j : (TA_ - 1 - j);
    {  // stage patch column t -> p_lds (bf16)
      int r = tid >> 2, q = (tid & 3) << 2;
      const float4 v = *(const float4*)(patches + ((size_t)(b0 + r) * TA_ + t) * 16 + q);
      u16* d = &p_lds[r * 40 + q];
      d[0] = f2bf(v.x); d[1] = f2bf(v.y); d[2] = f2bf(v.z); d[3] = f2bf(v.w);
    }
    if (j > 0 && tid == 0) {
      while (__hip_atomic_load(cnt + (j - 1), __ATOMIC_RELAXED, __HIP_MEMORY_SCOPE_AGENT) < 16)
        __builtin_amdgcn_s_sleep(2);
    }
    __syncthreads();
    __threadfence();  // acquire: make other slices' h_{t-1} visible

    f32x4 acc_i = {0,0,0,0}, acc_f = {0,0,0,0}, acc_g = {0,0,0,0}, acc_o = {0,0,0,0};
    {  // patch projection (folded embed + Wih), one k-step
      short8 a = *(const short8*)&p_lds[(m0 + cl) * 40 + kq * 8];
      acc_i = mfma_bf16(a, *(const short8*)&Wc_lds[cl * 40 + kq * 8], acc_i);
      acc_f = mfma_bf16(a, *(const short8*)&Wc_lds[(16 + cl) * 40 + kq * 8], acc_f);
      acc_g = mfma_bf16(a, *(const short8*)&Wc_lds[(32 + cl) * 40 + kq * 8], acc_g);
      acc_o = mfma_bf16(a, *(const short8*)&Wc_lds[(48 + cl) * 40 + kq * 8], acc_o);
    }
    if (j > 0) {  // h_{t-1} @ Whh
      const int tp = fwd ? (t - 1) : (t + 1);
      const u16* Ap = hbi + ((size_t)(b0 + m0 + cl) * TA_ + tp) * 512 + halfoff + kq * 8;
#pragma unroll
      for (int kk = 0; kk < 8; ++kk) {
        short8 a = *(const short8*)(Ap + kk * 32);
        acc_i = mfma_bf16(a, *(const short8*)&W_lds[cl * 264 + kk * 32 + kq * 8], acc_i);
        acc_f = mfma_bf16(a, *(const short8*)&W_lds[(16 + cl) * 264 + kk * 32 + kq * 8], acc_f);
        acc_g = mfma_bf16(a, *(const short8*)&W_lds[(32 + cl) * 264 + kk * 32 + kq * 8], acc_g);
        acc_o = mfma_bf16(a, *(const short8*)&W_lds[(48 + cl) * 264 + kk * 32 + kq * 8], acc_o);
      }
    }
    f32x4 hv;
#pragma unroll
    for (int r = 0; r < 4; ++r) {
      float iv = sigm(acc_i[r] + bs_i);
      float fv = sigm(acc_f[r] + bs_f);
      float gv = tanh_fast(acc_g[r] + bs_g);
      float ov = sigm(acc_o[r] + bs_o);
      float cc = fv * c_st[r] + iv * gv;
      c_st[r] = cc;
      hv[r] = ov * tanh_fast(cc);
    }
#pragma unroll
    for (int r = 0; r < 4; ++r) {
      int row = b0 + m0 + (kq << 2) + r;
      hbi[((size_t)row * TA_ + t) * 512 + halfoff + c0 + cl] = f2bf(hv[r]);
    }
    __threadfence();  // release
    __syncthreads();
    if (tid == 0)
      __hip_atomic_fetch_add(cnt + j, 1, __ATOMIC_RELEASE, __HIP_MEMORY_SCOPE_AGENT);
  }
}

__device__ __forceinline__ void gru_path(
    int wg, const float* __restrict__ patches, const u16* __restrict__ Wt,
    const u16* __restrict__ Wc, const float* __restrict__ biasx, const float* __restrict__ bhh,
    u16* __restrict__ h_hist, float* __restrict__ h_seq, int* cnt, u16* lds) {
  const int tid = threadIdx.x;
  const int lane = tid & 63, wv = tid >> 6;
  const int g = wg >> 5, s = wg & 31;
  const int b0 = g << 6;
  const int c0 = s << 4;  // h-col base within 512
  u16* W_lds = lds;              // [48][520]
  u16* p_lds = lds + 48 * 520;   // [64][40]
  u16* Wc_lds = p_lds + 64 * 40; // [48][40]

  for (int idx = tid; idx < 3072; idx += 256) {
    int n = idx >> 6, k8 = (idx & 63) << 3;
    int grow = ((n >> 4) << 9) + c0 + (n & 15);
    *(short8*)&W_lds[n * 520 + k8] = *(const short8*)&Wt[(size_t)grow * 512 + k8];
  }
  {
    int idx = tid;
    if (idx < 192) {
      int n = idx >> 2, k8 = (idx & 3) << 3;
      int grow = ((n >> 4) << 9) + c0 + (n & 15);
      *(short8*)&Wc_lds[n * 40 + k8] = *(const short8*)&Wc[(size_t)grow * 32 + k8];
    }
  }
  for (int idx = tid; idx < 2560; idx += 256) p_lds[idx] = 0;

  const int cl = lane & 15, kq = lane >> 4;
  const int colg = c0 + cl;
  const float b_r = biasx[colg] + bhh[colg];
  const float b_z = biasx[512 + colg] + bhh[512 + colg];
  const float b_xn = biasx[1024 + colg];
  const float b_hn = bhh[1024 + colg];
  const int m0 = wv << 4;
  f32x4 h_st = {0.f, 0.f, 0.f, 0.f};

  __syncthreads();

  for (int j = 0; j < TH_; ++j) {
    {
      int r = tid >> 2, q = (tid & 3) << 2;
      const float4 v = *(const float4*)(patches + ((size_t)(b0 + r) * TH_ + j) * 16 + q);
      u16* d = &p_lds[r * 40 + q];
      d[0] = f2bf(v.x); d[1] = f2bf(v.y); d[2] = f2bf(v.z); d[3] = f2bf(v.w);
    }
    if (j > 0 && tid == 0) {
      while (__hip_atomic_load(cnt + (j - 1), __ATOMIC_RELAXED, __HIP_MEMORY_SCOPE_AGENT) < 32)
        __builtin_amdgcn_s_sleep(2);
    }
    __syncthreads();
    __threadfence();

    f32x4 acc_r = {0,0,0,0}, acc_z = {0,0,0,0}, acc_xn = {0,0,0,0}, acc_hn = {0,0,0,0};
    {
      short8 a = *(const short8*)&p_lds[(m0 + cl) * 40 + kq * 8];
      acc_r  = mfma_bf16(a, *(const short8*)&Wc_lds[cl * 40 + kq * 8], acc_r);
      acc_z  = mfma_bf16(a, *(const short8*)&Wc_lds[(16 + cl) * 40 + kq * 8], acc_z);
      acc_xn = mfma_bf16(a, *(const short8*)&Wc_lds[(32 + cl) * 40 + kq * 8], acc_xn);
    }
    if (j > 0) {
      const u16* Ap = h_hist + ((size_t)(b0 + m0 + cl) * TH_ + (j - 1)) * 512 + kq * 8;
#pragma unroll
      for (int kk = 0; kk < 16; ++kk) {
        short8 a = *(const short8*)(Ap + kk * 32);
        acc_r  = mfma_bf16(a, *(const short8*)&W_lds[cl * 520 + kk * 32 + kq * 8], acc_r);
        acc_z  = mfma_bf16(a, *(const short8*)&W_lds[(16 + cl) * 520 + kk * 32 + kq * 8], acc_z);
        acc_hn = mfma_bf16(a, *(const short8*)&W_lds[(32 + cl) * 520 + kk * 32 + kq * 8], acc_hn);
      }
    }
    f32x4 hv;
#pragma unroll
    for (int r = 0; r < 4; ++r) {
      float rv = sigm(acc_r[r] + b_r);
      float zv = sigm(acc_z[r] + b_z);
      float nv = tanh_fast(acc_xn[r] + b_xn + rv * (acc_hn[r] + b_hn));
      float h = (1.f - zv) * nv + zv * h_st[r];
      h_st[r] = h;
      hv[r] = h;
    }
#pragma unroll
    for (int r = 0; r < 4; ++r) {
      int row = b0 + m0 + (kq << 2) + r;
      size_t off = ((size_t)row * TH_ + j) * 512 + colg;
      h_hist[off] = f2bf(hv[r]);
      h_seq[off] = hv[r];
    }
    __threadfence();
    __syncthreads();
    if (tid == 0)
      __hip_atomic_fetch_add(cnt + j, 1, __ATOMIC_RELEASE, __HIP_MEMORY_SCOPE_AGENT);
  }
}

__global__ __launch_bounds__(256, 1) void k_recur(
    const float* __restrict__ patches_hist, const float* __restrict__ patches_all,
    const u16* __restrict__ Wt_f, const u16* __restrict__ Wt_b, const u16* __restrict__ Wt_g,
    const u16* __restrict__ Wc_f, const u16* __restrict__ Wc_b, const u16* __restrict__ Wc_g,
    const float* __restrict__ bias_lf, const float* __restrict__ bias_lb,
    const float* __restrict__ biasx_g, const float* __restrict__ bhh_g,
    u16* __restrict__ hbi, u16* __restrict__ h_hist, float* __restrict__ h_seq,
    int* cnt_lf, int* cnt_lb, int* cnt_g) {
  __shared__ __align__(16) u16 lds[29440];
  int blk = blockIdx.x;
  if (blk < 64) {
    int wg = blk;
    lstm_path(wg, patches_all, Wt_f, Wc_f, bias_lf, hbi, 0, cnt_lf + (wg >> 4) * TA_, 1, lds);
  } else if (blk < 128) {
    int wg = blk - 64;
    lstm_path(wg, patches_all, Wt_b, Wc_b, bias_lb, hbi, 256, cnt_lb + (wg >> 4) * TA_, 0, lds);
  } else {
    int wg = blk - 128;
    gru_path(wg, patches_hist, Wt_g, Wc_g, biasx_g, bhh_g, h_hist, h_seq,
             cnt_g + (wg >> 5) * TH_, lds);
  }
}

// ---------------- head GEMMs ----------------

// out1 = A@W1 + b1 ; out2 = softplus(A@W2 + b2)+1e-5 ; optional z = out1 + out2*eps (t<TH)
// A: [rows][512] bf16, Bw: [256][512] bf16 (rows 0..127 = W1^T, 128..255 = W2^T)
__global__ __launch_bounds__(256, 2) void k_ngemm(
    const u16* __restrict__ A, const u16* __restrict__ Bw, const float* __restrict__ b1,
    const float* __restrict__ b2, float* __restrict__ out1, float* __restrict__ out2,
    const float* __restrict__ eps, u16* __restrict__ z_out, int Tdim) {
  const int tid = threadIdx.x, lane = tid & 63, wv = tid >> 6;
  const int cl = lane & 15, kq = lane >> 4;
  const int row0 = blockIdx.x * 64 + wv * 16;
  f32x4 acc[16];
#pragma unroll
  for (int i = 0; i < 16; ++i) acc[i] = f32x4{0.f, 0.f, 0.f, 0.f};
  const u16* Ap = A + (size_t)(row0 + cl) * 512 + kq * 8;
  const u16* Bp = Bw + (size_t)cl * 512 + kq * 8;
  for (int kk = 0; kk < 16; ++kk) {
    short8 a = *(const short8*)(Ap + kk * 32);
#pragma unroll
    for (int nt = 0; nt < 16; ++nt) {
      short8 b = *(const short8*)(Bp + nt * 8192 + kk * 32);
      acc[nt] = mfma_bf16(a, b, acc[nt]);
    }
  }
#pragma unroll
  for (int nt = 0; nt < 8; ++nt) {
    const int col = nt * 16 + cl;
    const float bm = b1[col], bs = b2[col];
#pragma unroll
    for (int r = 0; r < 4; ++r) {
      const int row = row0 + (kq << 2) + r;
      float m = acc[nt][r] + bm;
      float sv = softplus_f(acc[nt + 8][r] + bs) + 1e-5f;
      out1[(size_t)row * 128 + col] = m;
      out2[(size_t)row * 128 + col] = sv;
      if (eps) {
        int bidx = row / Tdim, t = row - bidx * Tdim;
        if (t < TH_) {
          size_t zo = ((size_t)bidx * TH_ + t) * 128 + col;
          z_out[zo] = f2bf(m + sv * eps[zo]);
        }
      }
    }
  }
}

// e_act = gelu([h|z] @ W_e1 + b_e1), K=640
__global__ __launch_bounds__(256, 2) void k_e1(
    const u16* __restrict__ h_hist, const u16* __restrict__ z_hist,
    const u16* __restrict__ We1_t, const float* __restrict__ b_e1, u16* __restrict__ e_act) {
  const int tid = threadIdx.x, lane = tid & 63, wv = tid >> 6;
  const int cl = lane & 15, kq = lane >> 4;
  const int row0 = blockIdx.x * 128 + wv * 32;
  const int n0 = blockIdx.y * 128;
  f32x4 acc[2][8];
#pragma unroll
  for (int i = 0; i < 2; ++i)
#pragma unroll
    for (int j = 0; j < 8; ++j) acc[i][j] = f32x4{0.f, 0.f, 0.f, 0.f};
  const u16* A0 = h_hist + (size_t)(row0 + cl) * 512 + kq * 8;
  const u16* A1 = A0 + 16 * 512;
  const u16* Z0 = z_hist + (size_t)(row0 + cl) * 128 + kq * 8;
  const u16* Z1 = Z0 + 16 * 128;
  const u16* Bp = We1_t + (size_t)(n0 + cl) * 640 + kq * 8;
  for (int kk = 0; kk < 16; ++kk) {
    short8 a0 = *(const short8*)(A0 + kk * 32);
    short8 a1 = *(const short8*)(A1 + kk * 32);
#pragma unroll
    for (int nt = 0; nt < 8; ++nt) {
      short8 b = *(const short8*)(Bp + (size_t)nt * 16 * 640 + kk * 32);
      acc[0][nt] = mfma_bf16(a0, b, acc[0][nt]);
      acc[1][nt] = mfma_bf16(a1, b, acc[1][nt]);
    }
  }
  for (int kk = 0; kk < 4; ++kk) {
    short8 a0 = *(const short8*)(Z0 + kk * 32);
    short8 a1 = *(const short8*)(Z1 + kk * 32);
#pragma unroll
    for (int nt = 0; nt < 8; ++nt) {
      short8 b = *(const short8*)(Bp + (size_t)nt * 16 * 640 + (16 + kk) * 32);
      acc[0][nt] = mfma_bf16(a0, b, acc[0][nt]);
      acc[1][nt] = mfma_bf16(a1, b, acc[1][nt]);
    }
  }
#pragma unroll
  for (int nt = 0; nt < 8; ++nt) {
    const int col = n0 + nt * 16 + cl;
    const float bb = b_e1[col];
#pragma unroll
    for (int rt = 0; rt < 2; ++rt)
#pragma unroll
      for (int r = 0; r < 4; ++r) {
        const int row = row0 + rt * 16 + (kq << 2) + r;
        float v = acc[rt][nt][r] + bb;
        float gv = 0.5f * v * (1.f + erff(v * 0.70710678118654752f));
        e_act[(size_t)row * 512 + col] = f2bf(gv);
      }
  }
}

// y += (e_act @ W_e2) @ W_head  (b_e2.W_head + b_head pre-folded into y init)
__global__ __launch_bounds__(256, 2) void k_e2(
    const u16* __restrict__ Aact, const u16* __restrict__ We2_t, const float* __restrict__ Wh,
    float* __restrict__ y) {
  const int tid = threadIdx.x, lane = tid & 63, wv = tid >> 6;
  const int cl = lane & 15, kq = lane >> 4;
  const int row0 = blockIdx.x * 128 + wv * 32;
  const int n0 = blockIdx.y * 128;
  f32x4 acc[2][8];
#pragma unroll
  for (int i = 0; i < 2; ++i)
#pragma unroll
    for (int j = 0; j < 8; ++j) acc[i][j] = f32x4{0.f, 0.f, 0.f, 0.f};
  const u16* A0 = Aact + (size_t)(row0 + cl) * 512 + kq * 8;
  const u16* A1 = A0 + 16 * 512;
  const u16* Bp = We2_t + (size_t)(n0 + cl) * 512 + kq * 8;
  for (int kk = 0; kk < 16; ++kk) {
    short8 a0 = *(const short8*)(A0 + kk * 32);
    short8 a1 = *(const short8*)(A1 + kk * 32);
#pragma unroll
    for (int nt = 0; nt < 8; ++nt) {
      short8 b = *(const short8*)(Bp + (size_t)nt * 8192 + kk * 32);
      acc[0][nt] = mfma_bf16(a0, b, acc[0][nt]);
      acc[1][nt] = mfma_bf16(a1, b, acc[1][nt]);
    }
  }
  f32x4 ps0 = {0.f, 0.f, 0.f, 0.f}, ps1 = {0.f, 0.f, 0.f, 0.f};
#pragma unroll
  for (int nt = 0; nt < 8; ++nt) {
    const float wh = Wh[n0 + nt * 16 + cl];
#pragma unroll
    for (int r = 0; r < 4; ++r) {
      ps0[r] += acc[0][nt][r] * wh;
      ps1[r] += acc[1][nt][r] * wh;
    }
  }
#pragma unroll
  for (int off = 1; off < 16; off <<= 1) {
#pragma unroll
    for (int r = 0; r < 4; ++r) {
      ps0[r] += __shfl_xor(ps0[r], off, 64);
      ps1[r] += __shfl_xor(ps1[r], off, 64);
    }
  }
  if (cl == 0) {
#pragma unroll
    for (int r = 0; r < 4; ++r) {
      atomicAdd(&y[row0 + (kq << 2) + r], ps0[r]);
      atomicAdd(&y[row0 + 16 + (kq << 2) + r], ps1[r]);
    }
  }
}

// ---------------- launch ----------------

extern "C" void kernel_launch(void* const* d_in, const int* in_sizes, int n_in,
                              void* d_out, int out_size, void* d_ws, size_t ws_size,
                              hipStream_t stream) {
  const float* patches_hist = (const float*)d_in[0];
  const float* patches_all  = (const float*)d_in[1];
  const float* eps    = (const float*)d_in[2];
  const float* W_embed = (const float*)d_in[3];
  const float* b_embed = (const float*)d_in[4];
  const float* Wih_f = (const float*)d_in[5];
  const float* Whh_f = (const float*)d_in[6];
  const float* bih_f = (const float*)d_in[7];
  const float* bhh_f = (const float*)d_in[8];
  const float* Wih_b = (const float*)d_in[9];
  const float* Whh_b = (const float*)d_in[10];
  const float* bih_b = (const float*)d_in[11];
  const float* bhh_b = (const float*)d_in[12];
  const float* Wqm = (const float*)d_in[13];
  const float* bqm = (const float*)d_in[14];
  const float* Wqs = (const float*)d_in[15];
  const float* bqs = (const float*)d_in[16];
  const float* Wih_g = (const float*)d_in[17];
  const float* Whh_g = (const float*)d_in[18];
  const float* bih_g = (const float*)d_in[19];
  const float* bhh_g = (const float*)d_in[20];
  const float* Wpm = (const float*)d_in[21];
  const float* bpm = (const float*)d_in[22];
  const float* Wps = (const float*)d_in[23];
  const float* bps = (const float*)d_in[24];
  const float* W_e1 = (const float*)d_in[25];
  const float* b_e1 = (const float*)d_in[26];
  const float* W_e2 = (const float*)d_in[27];
  const float* b_e2 = (const float*)d_in[28];
  const float* W_head = (const float*)d_in[29];
  const float* b_head = (const float*)d_in[30];

  float* out = (float*)d_out;
  float* y_out  = out;                 // [256*512]
  float* pm_out = out + 131072;        // [256*512*128]
  float* ps_out = out + 16908288;
  float* qm_out = out + 33685504;      // [256*576*128]
  float* qs_out = out + 52559872;
  float* hs_out = out + 71434240;      // [256*512*512]

  char* w = (char*)d_ws;
  u16* hbi = (u16*)w;      w += (size_t)150994944;  // [B][TA][512] bf16 (hf|hb); later e_act
  u16* h_hist = (u16*)w;   w += (size_t)134217728;  // [B][TH][512] bf16 GRU h
  u16* z_hist = (u16*)w;   w += (size_t)33554432;   // [B][TH][128] bf16
  u16* Wt_f = (u16*)w;     w += 524288;             // [1024][256]
  u16* Wt_b = (u16*)w;     w += 524288;
  u16* Wt_g = (u16*)w;     w += 1572864;            // [1536][512]
  u16* Wq_t = (u16*)w;     w += 262144;             // [256][512]
  u16* Wp_t = (u16*)w;     w += 262144;
  u16* We1_t = (u16*)w;    w += 655360;             // [512][640]
  u16* We2_t = (u16*)w;    w += 524288;             // [512][512]
  u16* Wc_f = (u16*)w;     w += 65536;              // [1024][32]
  u16* Wc_b = (u16*)w;     w += 65536;
  u16* Wc_g = (u16*)w;     w += 98304;              // [1536][32]
  float* bias_lf = (float*)w; w += 4096;            // [1024] = be@Wih + bih + bhh
  float* bias_lb = (float*)w; w += 4096;
  float* biasx_g = (float*)w; w += 6144;            // [1536] = be@Wih + bih
  int* cnt_lf = (int*)w;   w += 9216;               // [4][576]
  int* cnt_lb = (int*)w;   w += 9216;
  int* cnt_g = (int*)w;    w += 8192;               // [4][512]
  u16* e_act = hbi;  // alias: hbi dead after k_ngemm(qm/qs)

  // prep
  k_init<<<512, 256, 0, stream>>>(cnt_lf, 6656, y_out, 131072, b_e2, W_head, b_head);
  k_transpose_cvt<<<1024, 256, 0, stream>>>(Whh_f, Wt_f, 256, 1024);
  k_transpose_cvt<<<1024, 256, 0, stream>>>(Whh_b, Wt_b, 256, 1024);
  k_transpose_cvt<<<3072, 256, 0, stream>>>(Whh_g, Wt_g, 512, 1536);
  k_transpose_cvt<<<256, 256, 0, stream>>>(Wqm, Wq_t, 512, 128);
  k_transpose_cvt<<<256, 256, 0, stream>>>(Wqs, Wq_t + 65536, 512, 128);
  k_transpose_cvt<<<256, 256, 0, stream>>>(Wpm, Wp_t, 512, 128);
  k_transpose_cvt<<<256, 256, 0, stream>>>(Wps, Wp_t + 65536, 512, 128);
  k_transpose_cvt<<<1280, 256, 0, stream>>>(W_e1, We1_t, 640, 512);
  k_transpose_cvt<<<1024, 256, 0, stream>>>(W_e2, We2_t, 512, 512);
  k_wcomb<<<128, 256, 0, stream>>>(W_embed, Wih_f, 1024, Wc_f);
  k_wcomb<<<128, 256, 0, stream>>>(W_embed, Wih_b, 1024, Wc_b);
  k_wcomb<<<192, 256, 0, stream>>>(W_embed, Wih_g, 1536, Wc_g);
  k_biasx<<<4, 256, 0, stream>>>(b_embed, Wih_f, bih_f, bhh_f, 1024, bias_lf);
  k_biasx<<<4, 256, 0, stream>>>(b_embed, Wih_b, bih_b, bhh_b, 1024, bias_lb);
  k_biasx<<<6, 256, 0, stream>>>(b_embed, Wih_g, bih_g, nullptr, 1536, biasx_g);

  // recurrences (persistent, 256 WGs: 64 LSTM-f, 64 LSTM-b, 128 GRU)
  k_recur<<<256, 256, 0, stream>>>(patches_hist, patches_all, Wt_f, Wt_b, Wt_g,
                                   Wc_f, Wc_b, Wc_g, bias_lf, bias_lb, biasx_g, bhh_g,
                                   hbi, h_hist, hs_out, cnt_lf, cnt_lb, cnt_g);

  // posterior heads + z ; prior heads
  k_ngemm<<<2304, 256, 0, stream>>>(hbi, Wq_t, bqm, bqs, qm_out, qs_out, eps, z_hist, 576);
  k_ngemm<<<2048, 256, 0, stream>>>(h_hist, Wp_t, bpm, bps, pm_out, ps_out, nullptr, nullptr, 512);

  // emission MLP + head
  k_e1<<<dim3(1024, 4), 256, 0, stream>>>(h_hist, z_hist, We1_t, b_e1, e_act);
  k_e2<<<dim3(1024, 4), 256, 0, stream>>>(e_act, We2_t, W_head, y_out);
}